// Round 4
// baseline (938.808 us; speedup 1.0000x reference)
//
#include <hip/hip_runtime.h>
#include <stdint.h>

// Problem constants (fixed): x is (B=2, N=8192, D=64) f32, K=16. Ref is f64-exact.
constexpr int B_  = 2;
constexpr int N_  = 8192;
constexpr int D_  = 64;
constexpr int K_  = 16;
constexpr int NQ  = B_ * N_;          // 16384 queries
constexpr int S2  = 16;               // filter slices
constexpr int SL2 = N_ / S2;          // 512 candidates per filter slice
constexpr int CAP = 32;               // per (query,slice) survivor capacity (E~8)
constexpr int CHUNK = 64;             // candidates staged per LDS chunk (16 KB)
constexpr int NCHUNK = SL2 / CHUNK;   // 8
constexpr int QPB3 = 16;              // queries per rerank block (x16 slices = 256 thr)
constexpr int TQ = 64;                // queries per tau block
constexpr int TT = 8;                 // teams (waves) per tau block
constexpr int TSAMP = 1024;           // tau sample size (contiguous prefix; any subset is valid)

// ---- sorted ascending top-J insert chains (predicated cndmask ladders) ----
template<int JN>
__device__ __forceinline__ void topk_insertf(float (&key)[JN], float nk) {
    if (nk < key[JN - 1]) {
        bool c[JN];
#pragma unroll
        for (int j = 0; j < JN; ++j) c[j] = nk < key[j];
#pragma unroll
        for (int j = JN - 1; j >= 1; --j)
            key[j] = c[j - 1] ? key[j - 1] : (c[j] ? nk : key[j]);
        key[0] = c[0] ? nk : key[0];
    }
}
template<int JN>
__device__ __forceinline__ void topk_insert64(unsigned long long (&key)[JN], unsigned long long nk) {
    if (nk < key[JN - 1]) {
        bool c[JN];
#pragma unroll
        for (int j = 0; j < JN; ++j) c[j] = nk < key[j];
#pragma unroll
        for (int j = JN - 1; j >= 1; --j)
            key[j] = c[j - 1] ? key[j - 1] : (c[j] ? nk : key[j]);
        key[0] = c[0] ? nk : key[0];
    }
}

// K1: squared norms per point.
__global__ void __launch_bounds__(256) norms_k(const float* __restrict__ x, float* __restrict__ nrm) {
    int i = blockIdx.x * 256 + threadIdx.x;
    const float4* p = reinterpret_cast<const float4*>(x + (size_t)i * D_);
    float a0 = 0.f, a1 = 0.f, a2 = 0.f, a3 = 0.f;
#pragma unroll
    for (int j = 0; j < 16; ++j) {
        float4 v = p[j];
        a0 = fmaf(v.x, v.x, a0); a1 = fmaf(v.y, v.y, a1);
        a2 = fmaf(v.z, v.z, a2); a3 = fmaf(v.w, v.w, a3);
    }
    nrm[i] = (a0 + a1) + (a2 + a3);
}

// K2a: per-query threshold tau = 16th-smallest key over the first 1024 points
// (pigeonhole: valid filter bound for ANY subset). Block = 512 thr = 64 queries
// x 8 teams; samples staged through LDS in 64-point chunks; all teams active on
// every chunk (team t takes samples [t*8, t*8+8) of the chunk). grid = NQ/64.
__global__ void __launch_bounds__(512) tau_k(const float* __restrict__ x,
                                             const float* __restrict__ nrm,
                                             float* __restrict__ tau) {
    __shared__ float cbuf[CHUNK * D_];          // 16 KB staged samples
    __shared__ float mk[TT * TQ * 17];          // 34 KB merge buffer (stride 17: no conflicts)
    const int tid = (int)threadIdx.x;
    const int ql  = tid & 63;
    const int t   = tid >> 6;                   // team == wave index (uniform)
    const int q   = blockIdx.x * TQ + ql;
    const int b   = q >> 13;                    // uniform (64 | 8192)
    const int n   = q & (N_ - 1);
    const float* __restrict__ xb = x + (size_t)b * N_ * D_;
    const float4* qp = reinterpret_cast<const float4*>(xb + (size_t)n * D_);
    float4 Q[16];
#pragma unroll
    for (int j = 0; j < 16; ++j) Q[j] = qp[j];

    float key[K_];
#pragma unroll
    for (int j = 0; j < K_; ++j) key[j] = __builtin_inff();

    const float* __restrict__ nb = nrm + b * N_;
    const float4* gsrc = reinterpret_cast<const float4*>(xb);   // sample prefix base

    for (int c = 0; c < TSAMP / CHUNK; ++c) {   // 16 chunks
        if (c) __syncthreads();
        // stage chunk c: 64 samples x 64 floats = 1024 float4, 512 threads x 2
        const float4* g = gsrc + (size_t)c * CHUNK * (D_ / 4);
        float4* cb = reinterpret_cast<float4*>(cbuf);
        cb[tid]       = g[tid];
        cb[tid + 512] = g[tid + 512];
        __syncthreads();
#pragma unroll
        for (int j = 0; j < 8; ++j) {
            const int mi = t * 8 + j;           // uniform within wave
            const int m  = c * CHUNK + mi;
            const float4* cp = reinterpret_cast<const float4*>(cbuf + mi * D_);
            float a0 = 0.f, a1 = 0.f, a2 = 0.f, a3 = 0.f;
#pragma unroll
            for (int jj = 0; jj < 16; ++jj) {
                float4 cc = cp[jj];             // uniform LDS addr -> broadcast
                a0 = fmaf(Q[jj].x, cc.x, a0); a1 = fmaf(Q[jj].y, cc.y, a1);
                a2 = fmaf(Q[jj].z, cc.z, a2); a3 = fmaf(Q[jj].w, cc.w, a3);
            }
            float dot  = (a0 + a1) + (a2 + a3);
            float keyf = fmaf(-2.f, dot, nb[m]);
            topk_insertf<K_>(key, keyf);
        }
    }

    // tree merge 8 -> 1 team lists per query
    float* lp = mk + ((size_t)t * TQ + ql) * 17;
#pragma unroll
    for (int j = 0; j < K_; ++j) lp[j] = key[j];
    __syncthreads();
    for (int step = 4; step >= 1; step >>= 1) {
        if (t < step) {
            const float* sp = mk + ((size_t)(t + step) * TQ + ql) * 17;
            for (int j = 0; j < K_; ++j) topk_insertf<K_>(key, sp[j]);
#pragma unroll
            for (int j = 0; j < K_; ++j) lp[j] = key[j];
        }
        __syncthreads();
    }
    if (t == 0) tau[q] = key[15] + 4e-3f;   // slop >> f32 reassociation noise (~1e-4)
}

// K2b: filtered scan with LDS-staged broadcast candidates. Thread=query, block
// scans one 512-candidate slice in 8 chunks of 64 (16 KB LDS), register-prefetching
// chunk c+1 during compute of chunk c. Accepts (keyf <= tau) appended as u16 ids.
// grid = 64 qb x 16 s = 1024 blocks of 256.
__global__ void __launch_bounds__(256, 4) filter_k(const float* __restrict__ x,
                                                   const float* __restrict__ nrm,
                                                   const float* __restrict__ tau,
                                                   unsigned short* __restrict__ buf,
                                                   unsigned short* __restrict__ cnt) {
    __shared__ float cbuf[CHUNK * D_];          // 16 KB
    const int tid = (int)threadIdx.x;
    const int qb = blockIdx.x & 63;             // query block (uniform)
    const int s  = blockIdx.x >> 6;             // slice (uniform)
    const int b  = qb >> 5;                     // batch (uniform)
    const int n  = ((qb & 31) << 8) + tid;
    const int q  = (b << 13) + n;

    const float* __restrict__ xb = x + (size_t)b * N_ * D_;
    const float4* qp = reinterpret_cast<const float4*>(xb + (size_t)n * D_);
    float4 Q[16];
#pragma unroll
    for (int j = 0; j < 16; ++j) Q[j] = qp[j];

    const float tq = tau[q];
    const float* __restrict__ nb = nrm + b * N_;
    unsigned short* bp = buf + ((size_t)q * S2 + s) * CAP;
    int c = 0;
    const int m0 = s * SL2;

    const float4* gsrc = reinterpret_cast<const float4*>(xb + (size_t)m0 * D_);
    float4 pre[4];
#pragma unroll
    for (int k = 0; k < 4; ++k) pre[k] = gsrc[tid + k * 256];

    for (int ch = 0; ch < NCHUNK; ++ch) {
        if (ch) __syncthreads();
        float4* cb = reinterpret_cast<float4*>(cbuf);
#pragma unroll
        for (int k = 0; k < 4; ++k) cb[tid + k * 256] = pre[k];
        __syncthreads();
        if (ch + 1 < NCHUNK) {
            const float4* g = gsrc + (size_t)(ch + 1) * CHUNK * (D_ / 4);
#pragma unroll
            for (int k = 0; k < 4; ++k) pre[k] = g[tid + k * 256];
        }
        for (int mi = 0; mi < CHUNK; ++mi) {
            const int m = m0 + ch * CHUNK + mi;
            const float4* cp = reinterpret_cast<const float4*>(cbuf + mi * D_);
            float a0 = 0.f, a1 = 0.f, a2 = 0.f, a3 = 0.f;
#pragma unroll
            for (int j = 0; j < 16; ++j) {
                float4 cc = cp[j];              // uniform LDS addr -> broadcast
                a0 = fmaf(Q[j].x, cc.x, a0); a1 = fmaf(Q[j].y, cc.y, a1);
                a2 = fmaf(Q[j].z, cc.z, a2); a3 = fmaf(Q[j].w, cc.w, a3);
            }
            float dot  = (a0 + a1) + (a2 + a3);
            float keyf = fmaf(-2.f, dot, nb[m]);
            if (keyf <= tq) {                   // rare per-lane (~1.6%)
                if (c < CAP) bp[c] = (unsigned short)m;
                ++c;
            }
        }
    }
    cnt[(size_t)q * S2 + s] = (unsigned short)(c < CAP ? c : CAP);
}

// K3: exact f64 rerank of survivors; exact top-16 with index tie-break.
// 4 independent f64 accumulators (the single-acc version was a 256-deep dependent
// chain ~2000 cyc/candidate). block = 256 = 16 q x 16 slices; grid = NQ/16.
__global__ void __launch_bounds__(256, 4) rerank_k(const float* __restrict__ x,
                                                   const unsigned short* __restrict__ buf,
                                                   const unsigned short* __restrict__ cnt,
                                                   int* __restrict__ out) {
    __shared__ unsigned long long lds[QPB3 * 16 * K_];   // 32 KB
    const int t  = (int)threadIdx.x;
    const int qi = t >> 4;
    const int p  = t & 15;
    const int q  = blockIdx.x * QPB3 + qi;
    const int b  = q >> 13;
    const int n  = q & (N_ - 1);
    const float* __restrict__ xb = x + (size_t)b * N_ * D_;
    const float4* qp = reinterpret_cast<const float4*>(xb + (size_t)n * D_);
    float4 Q[16];
#pragma unroll
    for (int j = 0; j < 16; ++j) Q[j] = qp[j];

    unsigned long long key[K_];
#pragma unroll
    for (int j = 0; j < K_; ++j) key[j] = ~0ull;

    const int c = (int)cnt[(size_t)q * S2 + p];
    const unsigned short* bp = buf + ((size_t)q * S2 + p) * CAP;
    for (int i = 0; i < c; ++i) {
        int id = (int)bp[i];
        const float4* cp = reinterpret_cast<const float4*>(xb + (size_t)id * D_);
        double a0 = 0.0, a1 = 0.0, a2 = 0.0, a3 = 0.0;
#pragma unroll
        for (int j = 0; j < 16; ++j) {
            float4 cc = cp[j];
            double d0 = (double)Q[j].x - (double)cc.x; a0 = fma(d0, d0, a0);
            double d1 = (double)Q[j].y - (double)cc.y; a1 = fma(d1, d1, a1);
            double d2 = (double)Q[j].z - (double)cc.z; a2 = fma(d2, d2, a2);
            double d3 = (double)Q[j].w - (double)cc.w; a3 = fma(d3, d3, a3);
        }
        double acc = (a0 + a1) + (a2 + a3);
        // acc >= 0 -> f64 bits order-preserving; low 13 mantissa bits (2^-39 rel)
        // hold the id for exact (dist, id) lexicographic compare. Distinct-pair
        // distance gaps >> 1e-13 f64 noise; exact ties resolved by id.
        unsigned long long kb = (unsigned long long)__double_as_longlong(acc);
        unsigned long long nk = (kb & ~0x1FFFull) | (unsigned)id;
        topk_insert64<K_>(key, nk);
    }

    unsigned long long* lp = lds + ((size_t)qi * 16 + p) * K_;
#pragma unroll
    for (int j = 0; j < K_; ++j) lp[j] = key[j];
    __syncthreads();

    for (int step = 8; step >= 1; step >>= 1) {
        if (p < step) {
            const unsigned long long* sp = lds + ((size_t)qi * 16 + p + step) * K_;
            for (int i = 0; i < K_; ++i) topk_insert64<K_>(key, sp[i]);
#pragma unroll
            for (int j = 0; j < K_; ++j) lp[j] = key[j];
        }
        __syncthreads();
    }

    if (p == 0) {
        int* o1 = out + (size_t)q * K_;                       // nn_idx    [b][n][k]
        int* o2 = out + (size_t)NQ * K_ + (size_t)q * K_;     // center_idx[b][n][k]
#pragma unroll
        for (int kk = 0; kk < K_; ++kk) {
            o1[kk] = (int)(key[kk] & 0x1FFFull);
            o2[kk] = n;
        }
    }
}

extern "C" void kernel_launch(void* const* d_in, const int* in_sizes, int n_in,
                              void* d_out, int out_size, void* d_ws, size_t ws_size,
                              hipStream_t stream) {
    const float* x = (const float*)d_in[0];
    int* out = (int*)d_out;
    char* ws = (char*)d_ws;
    float* nrm = (float*)ws;                                   //  64 KB
    float* tau = (float*)(ws + (64 << 10));                    //  64 KB
    unsigned short* cnt = (unsigned short*)(ws + (128 << 10)); // 512 KB
    unsigned short* buf = (unsigned short*)(ws + (1 << 20));   // 16 MB (16384*16*32*2)

    hipLaunchKernelGGL(norms_k,  dim3(NQ / 256),  dim3(256), 0, stream, x, nrm);
    hipLaunchKernelGGL(tau_k,    dim3(NQ / TQ),   dim3(512), 0, stream, x, nrm, tau);
    hipLaunchKernelGGL(filter_k, dim3(64 * S2),   dim3(256), 0, stream, x, nrm, tau, buf, cnt);
    hipLaunchKernelGGL(rerank_k, dim3(NQ / QPB3), dim3(256), 0, stream, x, buf, cnt, out);
}

// Round 5
// 786.219 us; speedup vs baseline: 1.1941x; 1.1941x over previous
//
#include <hip/hip_runtime.h>
#include <stdint.h>

// KNN K=16 over x (B=2, N=8192, D=64) f32. Output int32 (2,B,N,K): nn_idx, center_idx.
// Pipeline: split_k (bf16 hi/lo + norms + cnt zero) -> tau_k (per-query provable
// threshold from 1024-sample, f32) -> filter_k (MFMA bf16 3-term split distance,
// accept key <= tau+SLOP, ~131 survivors/query) -> rerank_k (exact f64, coalesced).
constexpr int N_   = 8192;
constexpr int D_   = 64;
constexpr int K_   = 16;
constexpr int NQ   = 16384;           // 2*8192
constexpr int CAP2 = 384;             // survivor cap: E=128, sigma~30 -> +8.5 sigma
constexpr float SLOP = 0.01f;         // >= hard bound on bf16-split + f32-tau error (~4e-3)

typedef __attribute__((ext_vector_type(8))) short bf16x8;
typedef __attribute__((ext_vector_type(4))) float f32x4;

template<int JN>
__device__ __forceinline__ void topk_insertf(float (&key)[JN], float nk) {
    if (nk < key[JN - 1]) {
        bool c[JN];
#pragma unroll
        for (int j = 0; j < JN; ++j) c[j] = nk < key[j];
#pragma unroll
        for (int j = JN - 1; j >= 1; --j)
            key[j] = c[j - 1] ? key[j - 1] : (c[j] ? nk : key[j]);
        key[0] = c[0] ? nk : key[0];
    }
}
template<int JN>
__device__ __forceinline__ void topk_insert64(unsigned long long (&key)[JN], unsigned long long nk) {
    if (nk < key[JN - 1]) {
        bool c[JN];
#pragma unroll
        for (int j = 0; j < JN; ++j) c[j] = nk < key[j];
#pragma unroll
        for (int j = JN - 1; j >= 1; --j)
            key[j] = c[j - 1] ? key[j - 1] : (c[j] ? nk : key[j]);
        key[0] = c[0] ? nk : key[0];
    }
}

__device__ __forceinline__ unsigned short bf16_rne(float f) {
    uint32_t u = __float_as_uint(f);
    return (unsigned short)((u + 0x7FFFu + ((u >> 16) & 1u)) >> 16);   // no NaN in data
}

// K1: bf16 hi/lo split + squared norms + cnt2 zeroing. 16 lanes per row (coalesced).
// grid = NQ*16/256 = 1024.
__global__ void __launch_bounds__(256) split_k(const float* __restrict__ x,
                                               unsigned short* __restrict__ xh,
                                               unsigned short* __restrict__ xl,
                                               float* __restrict__ nrm,
                                               unsigned int* __restrict__ cnt2) {
    const int t = blockIdx.x * 256 + (int)threadIdx.x;    // one float4 per thread
    if (t < NQ) cnt2[t] = 0;                              // zero survivor counters
    const int row = t >> 4, seg = t & 15;
    const float4 v = reinterpret_cast<const float4*>(x)[t];
    float f[4] = {v.x, v.y, v.z, v.w};
    unsigned short h[4], l[4];
    float sq = 0.f;
#pragma unroll
    for (int j = 0; j < 4; ++j) {
        sq = fmaf(f[j], f[j], sq);
        h[j] = bf16_rne(f[j]);
        float hf = __uint_as_float((uint32_t)h[j] << 16);
        l[j] = bf16_rne(f[j] - hf);                       // residual exact in f32
    }
    // 16-lane norm reduce
    sq += __shfl_xor(sq, 1, 16); sq += __shfl_xor(sq, 2, 16);
    sq += __shfl_xor(sq, 4, 16); sq += __shfl_xor(sq, 8, 16);
    if (seg == 0) nrm[row] = sq;
    ushort4 hv = {h[0], h[1], h[2], h[3]}, lv = {l[0], l[1], l[2], l[3]};
    reinterpret_cast<ushort4*>(xh)[t] = hv;
    reinterpret_cast<ushort4*>(xl)[t] = lv;
}

// K2: per-query tau = 16th-smallest f32 key over first 1024 points + 4e-3.
// Pigeonhole: sample-16th >= full-16th -> provably lossless filter bound.
// block 256 = 16 queries x 16 teams; 1024 samples in 16 LDS chunks of 64.
// grid = NQ/16 = 1024 (4 blocks/CU at ~35 KB LDS).
constexpr int CROW = 68;   // padded chunk row (floats): 272 B -> bank phase 4/row
__global__ void __launch_bounds__(256, 4) tau_k(const float* __restrict__ x,
                                                const float* __restrict__ nrm,
                                                float* __restrict__ tau) {
    __shared__ float cb[64 * CROW];     // 17.4 KB staged samples
    __shared__ float mk[256 * 17];      // 17.4 KB merge buffer
    const int tid  = (int)threadIdx.x;
    const int ql   = tid & 15;
    const int team = tid >> 4;          // 0..15
    const int q    = blockIdx.x * 16 + ql;
    const int b    = q >> 13;           // uniform (16 | 8192)
    const int n    = q & (N_ - 1);
    const float* __restrict__ xb = x + (size_t)b * N_ * D_;
    const float4* qp = reinterpret_cast<const float4*>(xb + (size_t)n * D_);
    float4 Q[16];
#pragma unroll
    for (int j = 0; j < 16; ++j) Q[j] = qp[j];

    float key[K_];
#pragma unroll
    for (int j = 0; j < K_; ++j) key[j] = __builtin_inff();

    const float* __restrict__ nb = nrm + b * N_;
    for (int ch = 0; ch < 16; ++ch) {
        if (ch) __syncthreads();
#pragma unroll
        for (int k = 0; k < 4; ++k) {   // stage 64 rows x 16 float4 (coalesced)
            int u = tid + k * 256, r = u >> 4, s = u & 15;
            *(float4*)(cb + r * CROW + s * 4) =
                *(const float4*)(xb + (size_t)(ch * 64 + r) * D_ + s * 4);
        }
        __syncthreads();
#pragma unroll
        for (int j = 0; j < 4; ++j) {
            const int mi = team * 4 + j;
            const int m  = ch * 64 + mi;
            const float4* cp = reinterpret_cast<const float4*>(cb + mi * CROW);
            float a0 = 0.f, a1 = 0.f, a2 = 0.f, a3 = 0.f;
#pragma unroll
            for (int jj = 0; jj < 16; ++jj) {
                float4 cc = cp[jj];
                a0 = fmaf(Q[jj].x, cc.x, a0); a1 = fmaf(Q[jj].y, cc.y, a1);
                a2 = fmaf(Q[jj].z, cc.z, a2); a3 = fmaf(Q[jj].w, cc.w, a3);
            }
            float keyf = fmaf(-2.f, (a0 + a1) + (a2 + a3), nb[m]);
            topk_insertf<K_>(key, keyf);
        }
    }
    float* lp = mk + (size_t)(team * 16 + ql) * 17;
#pragma unroll
    for (int j = 0; j < K_; ++j) lp[j] = key[j];
    __syncthreads();
    for (int step = 8; step >= 1; step >>= 1) {
        if (team < step) {
            const float* sp = mk + (size_t)((team + step) * 16 + ql) * 17;
            for (int j = 0; j < K_; ++j) topk_insertf<K_>(key, sp[j]);
#pragma unroll
            for (int j = 0; j < K_; ++j) lp[j] = key[j];
        }
        __syncthreads();
    }
    if (team == 0) tau[q] = key[15] + 4e-3f;
}

// K3: MFMA filter. Tile 128q x 128m, K=64 (full rows). 3-term bf16 split:
// dot ~ qh.mh + qh.ml + ql.mh (err <= ~2e-3 by Cauchy-Schwarz on data norms).
// LDS rows padded to 144 B (2-way bank aliasing = free; 128 B would be 16-way).
// Fragments per verified gfx950 layouts: A/B [row=lane&15][k=quad*8+j],
// C/D col=lane&15, row=quad*4+reg. Accepts appended via device-scope atomics.
// grid = 2*64*64 = 8192 blocks of 256 (4 waves, each a 64x64 subtile).
__global__ void __launch_bounds__(256, 2) filter_k(const unsigned short* __restrict__ xh,
                                                   const unsigned short* __restrict__ xl,
                                                   const float* __restrict__ nrm,
                                                   const float* __restrict__ tau,
                                                   unsigned int* __restrict__ cnt2,
                                                   unsigned short* __restrict__ buf2) {
    __shared__ unsigned short Ah[128 * 72], Al[128 * 72], Bh[128 * 72], Bl[128 * 72]; // 72 KB
    __shared__ float taub[128], nrmb[128];
    const int tid = (int)threadIdx.x;
    const int bid = (int)blockIdx.x;
    const int b  = bid >> 12;
    const int qt = (bid >> 6) & 63;
    const int nt = bid & 63;
    const int q0 = qt * 128, n0 = nt * 128;
    const unsigned short* __restrict__ xhb = xh + (size_t)b * N_ * D_;
    const unsigned short* __restrict__ xlb = xl + (size_t)b * N_ * D_;

#pragma unroll
    for (int k = 0; k < 4; ++k) {       // stage 4 regions: 128 rows x 8 segs of 16 B
        int u = tid + k * 256, r = u >> 3, s = u & 7;
        *(float4*)((char*)Ah + r * 144 + s * 16) = *(const float4*)((const char*)(xhb + (size_t)(q0 + r) * D_) + s * 16);
        *(float4*)((char*)Al + r * 144 + s * 16) = *(const float4*)((const char*)(xlb + (size_t)(q0 + r) * D_) + s * 16);
        *(float4*)((char*)Bh + r * 144 + s * 16) = *(const float4*)((const char*)(xhb + (size_t)(n0 + r) * D_) + s * 16);
        *(float4*)((char*)Bl + r * 144 + s * 16) = *(const float4*)((const char*)(xlb + (size_t)(n0 + r) * D_) + s * 16);
    }
    if (tid < 128) {
        taub[tid] = tau[(b << 13) + q0 + tid];
        nrmb[tid] = nrm[(b << 13) + n0 + tid];
    }
    __syncthreads();

    const int wave = tid >> 6, lane = tid & 63;
    const int wq = wave >> 1, wm = wave & 1;        // wave subtile origin
    const int l15 = lane & 15, quad = lane >> 4;

    f32x4 acc[4][4] = {};
    const unsigned short* As[3] = {Ah, Ah, Al};
    const unsigned short* Bs[3] = {Bh, Bl, Bh};
#pragma unroll
    for (int sp = 0; sp < 3; ++sp) {
        const char* A = (const char*)As[sp];
        const char* Bt = (const char*)Bs[sp];
#pragma unroll
        for (int half = 0; half < 2; ++half) {
            const int ko = (half * 32 + quad * 8) * 2;
            bf16x8 af[4], bfr[4];
#pragma unroll
            for (int tm = 0; tm < 4; ++tm)
                af[tm] = *(const bf16x8*)(A + (wq * 64 + tm * 16 + l15) * 144 + ko);
#pragma unroll
            for (int tn = 0; tn < 4; ++tn)
                bfr[tn] = *(const bf16x8*)(Bt + (wm * 64 + tn * 16 + l15) * 144 + ko);
#pragma unroll
            for (int tm = 0; tm < 4; ++tm)
#pragma unroll
                for (int tn = 0; tn < 4; ++tn)
                    acc[tm][tn] = __builtin_amdgcn_mfma_f32_16x16x32_bf16(af[tm], bfr[tn], acc[tm][tn], 0, 0, 0);
        }
    }

    const int qbase = (b << 13) + q0 + wq * 64;
    const int mbase = n0 + wm * 64;
#pragma unroll
    for (int tm = 0; tm < 4; ++tm) {
        const f32x4 t4 = *(const f32x4*)(taub + wq * 64 + tm * 16 + quad * 4);
#pragma unroll
        for (int tn = 0; tn < 4; ++tn) {
            const float nm = nrmb[wm * 64 + tn * 16 + l15];
            const int mid = mbase + tn * 16 + l15;
#pragma unroll
            for (int reg = 0; reg < 4; ++reg) {
                float keyf = fmaf(-2.f, acc[tm][tn][reg], nm);
                if (keyf <= t4[reg] + SLOP) {            // rare (~1.6%)
                    int q = qbase + tm * 16 + quad * 4 + reg;
                    unsigned pos = atomicAdd(&cnt2[q], 1u);
                    if (pos < CAP2) buf2[(size_t)q * CAP2 + pos] = (unsigned short)mid;
                }
            }
        }
    }
}

// K4: exact f64 rerank. 16 lanes per query: per candidate one coalesced 256 B row
// load, 4 f64 FMA/lane, 4-step shfl_xor reduce; replicated top-16 ladder.
// block 256 = 16 queries; grid = NQ/16 = 1024.
__global__ void __launch_bounds__(256, 4) rerank_k(const float* __restrict__ x,
                                                   const unsigned int* __restrict__ cnt2,
                                                   const unsigned short* __restrict__ buf2,
                                                   int* __restrict__ out) {
    const int tid = (int)threadIdx.x;
    const int grp = tid >> 4, l = tid & 15;
    const int q = blockIdx.x * 16 + grp;
    const int b = q >> 13, n = q & (N_ - 1);
    const float* __restrict__ xb = x + (size_t)b * N_ * D_;
    const float4 Qv = *(const float4*)(xb + (size_t)n * D_ + l * 4);
    const double qx = Qv.x, qy = Qv.y, qz = Qv.z, qw = Qv.w;

    unsigned long long key[K_];
#pragma unroll
    for (int j = 0; j < K_; ++j) key[j] = ~0ull;

    int cn = (int)cnt2[q]; cn = cn < CAP2 ? cn : CAP2;
    const unsigned short* bp = buf2 + (size_t)q * CAP2;
    for (int i = 0; i < cn; ++i) {
        const int id = (int)bp[i];
        const float4 cv = *(const float4*)(xb + (size_t)id * D_ + l * 4);  // coalesced per group
        double d0 = qx - (double)cv.x, d1 = qy - (double)cv.y;
        double d2 = qz - (double)cv.z, d3 = qw - (double)cv.w;
        double s = fma(d0, d0, fma(d1, d1, fma(d2, d2, d3 * d3)));
        s += __shfl_xor(s, 1, 16); s += __shfl_xor(s, 2, 16);
        s += __shfl_xor(s, 4, 16); s += __shfl_xor(s, 8, 16);
        // s >= 0 -> f64 bits order-preserving; low 13 mantissa bits (2^-39 rel)
        // carry the id for exact (dist, id) lexicographic compare.
        unsigned long long kb = (unsigned long long)__double_as_longlong(s);
        topk_insert64<K_>(key, (kb & ~0x1FFFull) | (unsigned)id);
    }
    if (l == 0) {
        int* o1 = out + (size_t)q * K_;                    // nn_idx    [b][n][k]
        int* o2 = out + (size_t)NQ * K_ + (size_t)q * K_;  // center_idx[b][n][k]
#pragma unroll
        for (int kk = 0; kk < K_; ++kk) {
            o1[kk] = (int)(key[kk] & 0x1FFFull);
            o2[kk] = n;
        }
    }
}

extern "C" void kernel_launch(void* const* d_in, const int* in_sizes, int n_in,
                              void* d_out, int out_size, void* d_ws, size_t ws_size,
                              hipStream_t stream) {
    const float* x = (const float*)d_in[0];
    int* out = (int*)d_out;
    char* ws = (char*)d_ws;
    float*          nrm  = (float*)ws;                        //  64 KB @ 0
    float*          tau  = (float*)(ws + (64 << 10));         //  64 KB
    unsigned int*   cnt2 = (unsigned int*)(ws + (128 << 10)); //  64 KB
    unsigned short* xh   = (unsigned short*)(ws + (1 << 20)); //   2 MB
    unsigned short* xl   = (unsigned short*)(ws + (3 << 20)); //   2 MB
    unsigned short* buf2 = (unsigned short*)(ws + (5 << 20)); // 12.6 MB (16384*384*2)

    hipLaunchKernelGGL(split_k,  dim3(NQ * 16 / 256), dim3(256), 0, stream, x, xh, xl, nrm, cnt2);
    hipLaunchKernelGGL(tau_k,    dim3(NQ / 16),       dim3(256), 0, stream, x, nrm, tau);
    hipLaunchKernelGGL(filter_k, dim3(2 * 64 * 64),   dim3(256), 0, stream, xh, xl, nrm, tau, cnt2, buf2);
    hipLaunchKernelGGL(rerank_k, dim3(NQ / 16),       dim3(256), 0, stream, x, cnt2, buf2, out);
}

// Round 6
// 459.267 us; speedup vs baseline: 2.0441x; 1.7119x over previous
//
#include <hip/hip_runtime.h>
#include <stdint.h>

// KNN K=16 over x (B=2, N=8192, D=64) f32. Output int32 (2,B,N,K): nn_idx, center_idx.
// Pipeline: split_k (bf16 hi/lo + norms) -> tau_k (per-query provable threshold from
// 2048-sample, f32) -> filter_k (MFMA bf16 3-term split distance, B-reuse over 1024-m
// superblock, LDS-buffered accepts, NO global atomics) -> rerank_k (exact f64).
constexpr int N_   = 8192;
constexpr int D_   = 64;
constexpr int K_   = 16;
constexpr int NQ   = 16384;           // 2*8192
constexpr int MS   = 8;               // m-superblocks per batch (1024 m each)
constexpr int CAPB = 48;              // survivor cap per (query, m-superblock): E=8, +14 sigma
constexpr float SLOP = 0.012f;        // >= bf16-split dot err (~2e-3) + f32 norm/tau err
constexpr int TSAMP = 2048;           // tau sample size -> E[survivors] ~ 16*8192/2048 = 64

typedef __attribute__((ext_vector_type(8))) short bf16x8;
typedef __attribute__((ext_vector_type(4))) float f32x4;

template<int JN>
__device__ __forceinline__ void topk_insertf(float (&key)[JN], float nk) {
    if (nk < key[JN - 1]) {
        bool c[JN];
#pragma unroll
        for (int j = 0; j < JN; ++j) c[j] = nk < key[j];
#pragma unroll
        for (int j = JN - 1; j >= 1; --j)
            key[j] = c[j - 1] ? key[j - 1] : (c[j] ? nk : key[j]);
        key[0] = c[0] ? nk : key[0];
    }
}
template<int JN>
__device__ __forceinline__ void topk_insert64(unsigned long long (&key)[JN], unsigned long long nk) {
    if (nk < key[JN - 1]) {
        bool c[JN];
#pragma unroll
        for (int j = 0; j < JN; ++j) c[j] = nk < key[j];
#pragma unroll
        for (int j = JN - 1; j >= 1; --j)
            key[j] = c[j - 1] ? key[j - 1] : (c[j] ? nk : key[j]);
        key[0] = c[0] ? nk : key[0];
    }
}

__device__ __forceinline__ unsigned short bf16_rne(float f) {
    uint32_t u = __float_as_uint(f);
    return (unsigned short)((u + 0x7FFFu + ((u >> 16) & 1u)) >> 16);   // no NaN in data
}

// K1: bf16 hi/lo split + squared norms. 16 lanes per row (coalesced). grid = 1024.
__global__ void __launch_bounds__(256) split_k(const float* __restrict__ x,
                                               unsigned short* __restrict__ xh,
                                               unsigned short* __restrict__ xl,
                                               float* __restrict__ nrm) {
    const int t = blockIdx.x * 256 + (int)threadIdx.x;    // one float4 per thread
    const int row = t >> 4, seg = t & 15;
    const float4 v = reinterpret_cast<const float4*>(x)[t];
    float f[4] = {v.x, v.y, v.z, v.w};
    unsigned short h[4], l[4];
    float sq = 0.f;
#pragma unroll
    for (int j = 0; j < 4; ++j) {
        sq = fmaf(f[j], f[j], sq);
        h[j] = bf16_rne(f[j]);
        float hf = __uint_as_float((uint32_t)h[j] << 16);
        l[j] = bf16_rne(f[j] - hf);                       // residual exact in f32
    }
    sq += __shfl_xor(sq, 1, 16); sq += __shfl_xor(sq, 2, 16);
    sq += __shfl_xor(sq, 4, 16); sq += __shfl_xor(sq, 8, 16);
    if (seg == 0) nrm[row] = sq;
    ushort4 hv = {h[0], h[1], h[2], h[3]}, lv = {l[0], l[1], l[2], l[3]};
    reinterpret_cast<ushort4*>(xh)[t] = hv;
    reinterpret_cast<ushort4*>(xl)[t] = lv;
}

// K2: per-query tau = 16th-smallest f32 key over first 2048 points + 4e-3.
// Pigeonhole: sample-16th >= full-16th -> provably lossless filter bound.
// block 256 = 16 queries x 16 teams; 2048 samples in 32 LDS chunks of 64. grid = 1024.
constexpr int CROW = 68;   // padded chunk row (floats)
__global__ void __launch_bounds__(256, 4) tau_k(const float* __restrict__ x,
                                                const float* __restrict__ nrm,
                                                float* __restrict__ tau) {
    __shared__ float cb[64 * CROW];     // 17.4 KB staged samples
    __shared__ float mk[256 * 17];      // 17.4 KB merge buffer
    const int tid  = (int)threadIdx.x;
    const int ql   = tid & 15;
    const int team = tid >> 4;          // 0..15
    const int q    = blockIdx.x * 16 + ql;
    const int b    = q >> 13;           // uniform (16 | 8192)
    const int n    = q & (N_ - 1);
    const float* __restrict__ xb = x + (size_t)b * N_ * D_;
    const float4* qp = reinterpret_cast<const float4*>(xb + (size_t)n * D_);
    float4 Q[16];
#pragma unroll
    for (int j = 0; j < 16; ++j) Q[j] = qp[j];

    float key[K_];
#pragma unroll
    for (int j = 0; j < K_; ++j) key[j] = __builtin_inff();

    const float* __restrict__ nb = nrm + b * N_;
    for (int ch = 0; ch < TSAMP / 64; ++ch) {
        if (ch) __syncthreads();
#pragma unroll
        for (int k = 0; k < 4; ++k) {   // stage 64 rows x 16 float4 (coalesced)
            int u = tid + k * 256, r = u >> 4, s = u & 15;
            *(float4*)(cb + r * CROW + s * 4) =
                *(const float4*)(xb + (size_t)(ch * 64 + r) * D_ + s * 4);
        }
        __syncthreads();
#pragma unroll
        for (int j = 0; j < 4; ++j) {
            const int mi = team * 4 + j;
            const int m  = ch * 64 + mi;
            const float4* cp = reinterpret_cast<const float4*>(cb + mi * CROW);
            float a0 = 0.f, a1 = 0.f, a2 = 0.f, a3 = 0.f;
#pragma unroll
            for (int jj = 0; jj < 16; ++jj) {
                float4 cc = cp[jj];
                a0 = fmaf(Q[jj].x, cc.x, a0); a1 = fmaf(Q[jj].y, cc.y, a1);
                a2 = fmaf(Q[jj].z, cc.z, a2); a3 = fmaf(Q[jj].w, cc.w, a3);
            }
            float keyf = fmaf(-2.f, (a0 + a1) + (a2 + a3), nb[m]);
            topk_insertf<K_>(key, keyf);
        }
    }
    float* lp = mk + (size_t)(team * 16 + ql) * 17;
#pragma unroll
    for (int j = 0; j < K_; ++j) lp[j] = key[j];
    __syncthreads();
    for (int step = 8; step >= 1; step >>= 1) {
        if (team < step) {
            const float* sp = mk + (size_t)((team + step) * 16 + ql) * 17;
            for (int j = 0; j < K_; ++j) topk_insertf<K_>(key, sp[j]);
#pragma unroll
            for (int j = 0; j < K_; ++j) lp[j] = key[j];
        }
        __syncthreads();
    }
    if (team == 0) tau[q] = key[15] + 4e-3f;
}

// K3: MFMA filter, B-reuse. Block = 128q x 1024m (8 chunks of 128m). A (hi+lo,
// 32 KB) staged once; B per chunk (32 KB). 3-term bf16 split: qh.mh + qh.ml + ql.mh
// (err <= ~2e-3). XOR-swizzled LDS segs (seg^(row&7)) -> b128 reads at bank floor.
// Accepts -> LDS per-query lists (DS atomics only), flushed to fixed per-(q,ms)
// global slots. NO global atomics (R5's 450us was atomic-return stalls).
// grid = 2 * 64 * 8 = 1024 blocks of 256 (4 waves, each 64x64 per chunk).
#define SWZ(r, s) (((r) << 7) + ((((s) ^ ((r) & 7))) << 4))
__global__ void __launch_bounds__(256, 2) filter_k(const unsigned short* __restrict__ xh,
                                                   const unsigned short* __restrict__ xl,
                                                   const float* __restrict__ nrm,
                                                   const float* __restrict__ tau,
                                                   unsigned short* __restrict__ cnt_pb,
                                                   unsigned short* __restrict__ buf2) {
    __shared__ alignas(16) unsigned short A[256 * 64];    // 32 KB: rows 0-127 hi, 128-255 lo
    __shared__ alignas(16) unsigned short Bb[256 * 64];   // 32 KB
    __shared__ alignas(16) float taub[128];
    __shared__ unsigned short lists[128 * CAPB];          // 12 KB
    __shared__ unsigned int cntL[128];
    const int tid = (int)threadIdx.x;
    const int bid = (int)blockIdx.x;
    const int b  = bid >> 9;
    const int qt = (bid >> 3) & 63;
    const int ms = bid & 7;
    const int q0 = qt * 128;
    const unsigned short* __restrict__ xhb = xh + (size_t)b * N_ * D_;
    const unsigned short* __restrict__ xlb = xl + (size_t)b * N_ * D_;
    const float* __restrict__ nb = nrm + b * N_;

    // stage A (128 q-rows, hi then lo), zero counters, load tau tile
#pragma unroll
    for (int k = 0; k < 8; ++k) {
        int u = tid + k * 256, r = u >> 3, s = u & 7;     // r 0..255, s 0..7 (16 B segs)
        const unsigned short* src = (r < 128) ? xhb + (size_t)(q0 + r) * D_
                                              : xlb + (size_t)(q0 + r - 128) * D_;
        *(float4*)((char*)A + SWZ(r, s)) = *(const float4*)((const char*)src + (s << 4));
    }
    if (tid < 128) { cntL[tid] = 0; taub[tid] = tau[(b << 13) + q0 + tid]; }

    const int wave = tid >> 6, lane = tid & 63;
    const int wq = wave >> 1, wm = wave & 1;              // 64x64 wave subtile
    const int l15 = lane & 15, quad = lane >> 4;

    for (int mc = 0; mc < 8; ++mc) {
        const int m0 = ms * 1024 + mc * 128;
        __syncthreads();                                   // prev compute done / A visible
#pragma unroll
        for (int k = 0; k < 8; ++k) {                      // stage B chunk (hi+lo)
            int u = tid + k * 256, r = u >> 3, s = u & 7;
            const unsigned short* src = (r < 128) ? xhb + (size_t)(m0 + r) * D_
                                                  : xlb + (size_t)(m0 + r - 128) * D_;
            *(float4*)((char*)Bb + SWZ(r, s)) = *(const float4*)((const char*)src + (s << 4));
        }
        __syncthreads();

        f32x4 acc[4][4] = {};
#pragma unroll
        for (int sp = 0; sp < 3; ++sp) {
            const int abase = (sp == 2) ? 128 : 0;         // A: hi,hi,lo
            const int bbase = (sp == 1) ? 128 : 0;         // B: hi,lo,hi
#pragma unroll
            for (int half = 0; half < 2; ++half) {
                const int seg = half * 4 + quad;           // k-slice seg (16 B = 8 bf16)
                bf16x8 af[4], bfr[4];
#pragma unroll
                for (int tm = 0; tm < 4; ++tm) {
                    int r = abase + wq * 64 + tm * 16 + l15;
                    af[tm] = *(const bf16x8*)((const char*)A + SWZ(r, seg));
                }
#pragma unroll
                for (int tn = 0; tn < 4; ++tn) {
                    int r = bbase + wm * 64 + tn * 16 + l15;
                    bfr[tn] = *(const bf16x8*)((const char*)Bb + SWZ(r, seg));
                }
#pragma unroll
                for (int tm = 0; tm < 4; ++tm)
#pragma unroll
                    for (int tn = 0; tn < 4; ++tn)
                        acc[tm][tn] = __builtin_amdgcn_mfma_f32_16x16x32_bf16(af[tm], bfr[tn], acc[tm][tn], 0, 0, 0);
            }
        }

        // epilogue: C/D layout col=lane&15 (m), row=quad*4+reg (q)
#pragma unroll
        for (int tm = 0; tm < 4; ++tm) {
            const f32x4 t4 = *(const f32x4*)(taub + wq * 64 + tm * 16 + quad * 4);
#pragma unroll
            for (int tn = 0; tn < 4; ++tn) {
                const int mid = m0 + wm * 64 + tn * 16 + l15;
                const float nm = nb[mid];
#pragma unroll
                for (int reg = 0; reg < 4; ++reg) {
                    float keyf = fmaf(-2.f, acc[tm][tn][reg], nm);
                    if (keyf <= t4[reg] + SLOP) {
                        int ql = wq * 64 + tm * 16 + quad * 4 + reg;     // local q
                        unsigned pos = atomicAdd(&cntL[ql], 1u);         // LDS atomic
                        if (pos < CAPB) lists[ql * CAPB + pos] = (unsigned short)mid;
                    }
                }
            }
        }
    }
    __syncthreads();
    if (tid < 128) {                                       // flush to fixed slots
        int q = (b << 13) + q0 + tid;
        unsigned cn = cntL[tid]; cn = cn < CAPB ? cn : CAPB;
        cnt_pb[(size_t)q * MS + ms] = (unsigned short)cn;
        unsigned short* dst = buf2 + ((size_t)q * MS + ms) * CAPB;
        for (unsigned i = 0; i < cn; ++i) dst[i] = lists[tid * CAPB + i];
    }
}

// K4: exact f64 rerank. 16 lanes per query; per candidate one coalesced 256 B row
// load, 4 f64 FMA/lane, 4-step shfl reduce, u64 ladder (exact (dist,id) order).
// block 256 = 16 queries; grid = 1024.
__global__ void __launch_bounds__(256, 4) rerank_k(const float* __restrict__ x,
                                                   const unsigned short* __restrict__ cnt_pb,
                                                   const unsigned short* __restrict__ buf2,
                                                   int* __restrict__ out) {
    const int tid = (int)threadIdx.x;
    const int grp = tid >> 4, l = tid & 15;
    const int q = blockIdx.x * 16 + grp;
    const int b = q >> 13, n = q & (N_ - 1);
    const float* __restrict__ xb = x + (size_t)b * N_ * D_;
    const float4 Qv = *(const float4*)(xb + (size_t)n * D_ + l * 4);
    const double qx = Qv.x, qy = Qv.y, qz = Qv.z, qw = Qv.w;

    unsigned long long key[K_];
#pragma unroll
    for (int j = 0; j < K_; ++j) key[j] = ~0ull;

    for (int ms = 0; ms < MS; ++ms) {
        const int cn = (int)cnt_pb[(size_t)q * MS + ms];
        const unsigned short* bp = buf2 + ((size_t)q * MS + ms) * CAPB;
        for (int i = 0; i < cn; ++i) {
            const int id = (int)bp[i];
            const float4 cv = *(const float4*)(xb + (size_t)id * D_ + l * 4);
            double d0 = qx - (double)cv.x, d1 = qy - (double)cv.y;
            double d2 = qz - (double)cv.z, d3 = qw - (double)cv.w;
            double s = fma(d0, d0, fma(d1, d1, fma(d2, d2, d3 * d3)));
            s += __shfl_xor(s, 1, 16); s += __shfl_xor(s, 2, 16);
            s += __shfl_xor(s, 4, 16); s += __shfl_xor(s, 8, 16);
            // s >= 0 -> f64 bits order-preserving; low 13 mantissa bits carry the id
            // for exact (dist, id) lexicographic compare (ties -> lower id).
            unsigned long long kb = (unsigned long long)__double_as_longlong(s);
            topk_insert64<K_>(key, (kb & ~0x1FFFull) | (unsigned)id);
        }
    }
    if (l == 0) {
        int* o1 = out + (size_t)q * K_;                    // nn_idx    [b][n][k]
        int* o2 = out + (size_t)NQ * K_ + (size_t)q * K_;  // center_idx[b][n][k]
#pragma unroll
        for (int kk = 0; kk < K_; ++kk) {
            o1[kk] = (int)(key[kk] & 0x1FFFull);
            o2[kk] = n;
        }
    }
}

extern "C" void kernel_launch(void* const* d_in, const int* in_sizes, int n_in,
                              void* d_out, int out_size, void* d_ws, size_t ws_size,
                              hipStream_t stream) {
    const float* x = (const float*)d_in[0];
    int* out = (int*)d_out;
    char* ws = (char*)d_ws;
    float*          nrm    = (float*)ws;                         //  64 KB @ 0
    float*          tau    = (float*)(ws + (64 << 10));          //  64 KB
    unsigned short* cnt_pb = (unsigned short*)(ws + (128 << 10)); // 256 KB (16384*8*2)
    unsigned short* xh     = (unsigned short*)(ws + (1 << 20));  //   2 MB
    unsigned short* xl     = (unsigned short*)(ws + (3 << 20));  //   2 MB
    unsigned short* buf2   = (unsigned short*)(ws + (5 << 20));  // 12.6 MB (16384*8*48*2)

    hipLaunchKernelGGL(split_k,  dim3(1024), dim3(256), 0, stream, x, xh, xl, nrm);
    hipLaunchKernelGGL(tau_k,    dim3(1024), dim3(256), 0, stream, x, nrm, tau);
    hipLaunchKernelGGL(filter_k, dim3(1024), dim3(256), 0, stream, xh, xl, nrm, tau, cnt_pb, buf2);
    hipLaunchKernelGGL(rerank_k, dim3(1024), dim3(256), 0, stream, x, cnt_pb, buf2, out);
}

// Round 7
// 344.476 us; speedup vs baseline: 2.7253x; 1.3332x over previous
//
#include <hip/hip_runtime.h>
#include <stdint.h>

// KNN K=16 over x (B=2, N=8192, D=64) f32. Output int32 (2,B,N,K): nn_idx, center_idx.
// Pipeline: split_k (bf16 hi/lo + norms) -> tau_p (MFMA partial top-2 ladders over
// 2048-sample) -> tau_m (merge -> per-query provable threshold) -> filter_k (MFMA
// bf16 3-term split distance, LDS-buffered accepts, no global atomics) -> rerank_k
// (exact f64). Threshold correctness: 16th-smallest of ANY subset of sample keys
// >= sample-16th >= true d16 (pigeonhole); slop covers bf16-split approx error.
constexpr int N_   = 8192;
constexpr int D_   = 64;
constexpr int K_   = 16;
constexpr int NQ   = 16384;           // 2*8192
constexpr int MS   = 8;               // m-superblocks per batch (1024 m each)
constexpr int CAPB = 48;              // survivor cap per (query, m-superblock): E=8, +14 sigma
constexpr float SLOP = 0.012f;        // per-stage slop >> 2*eps(bf16-split ~1.3e-3)

typedef __attribute__((ext_vector_type(8))) short bf16x8;
typedef __attribute__((ext_vector_type(4))) float f32x4;

template<int JN>
__device__ __forceinline__ void topk_insertf(float (&key)[JN], float nk) {
    if (nk < key[JN - 1]) {
        bool c[JN];
#pragma unroll
        for (int j = 0; j < JN; ++j) c[j] = nk < key[j];
#pragma unroll
        for (int j = JN - 1; j >= 1; --j)
            key[j] = c[j - 1] ? key[j - 1] : (c[j] ? nk : key[j]);
        key[0] = c[0] ? nk : key[0];
    }
}
template<int JN>
__device__ __forceinline__ void topk_insert64(unsigned long long (&key)[JN], unsigned long long nk) {
    if (nk < key[JN - 1]) {
        bool c[JN];
#pragma unroll
        for (int j = 0; j < JN; ++j) c[j] = nk < key[j];
#pragma unroll
        for (int j = JN - 1; j >= 1; --j)
            key[j] = c[j - 1] ? key[j - 1] : (c[j] ? nk : key[j]);
        key[0] = c[0] ? nk : key[0];
    }
}

__device__ __forceinline__ unsigned short bf16_rne(float f) {
    uint32_t u = __float_as_uint(f);
    return (unsigned short)((u + 0x7FFFu + ((u >> 16) & 1u)) >> 16);   // no NaN in data
}

#define SWZ(r, s) (((r) << 7) + ((((s) ^ ((r) & 7))) << 4))

// K1: bf16 hi/lo split + squared norms. 16 lanes per row (coalesced). grid = 1024.
__global__ void __launch_bounds__(256) split_k(const float* __restrict__ x,
                                               unsigned short* __restrict__ xh,
                                               unsigned short* __restrict__ xl,
                                               float* __restrict__ nrm) {
    const int t = blockIdx.x * 256 + (int)threadIdx.x;    // one float4 per thread
    const int row = t >> 4, seg = t & 15;
    const float4 v = reinterpret_cast<const float4*>(x)[t];
    float f[4] = {v.x, v.y, v.z, v.w};
    unsigned short h[4], l[4];
    float sq = 0.f;
#pragma unroll
    for (int j = 0; j < 4; ++j) {
        sq = fmaf(f[j], f[j], sq);
        h[j] = bf16_rne(f[j]);
        float hf = __uint_as_float((uint32_t)h[j] << 16);
        l[j] = bf16_rne(f[j] - hf);                       // residual exact in f32
    }
    sq += __shfl_xor(sq, 1, 16); sq += __shfl_xor(sq, 2, 16);
    sq += __shfl_xor(sq, 4, 16); sq += __shfl_xor(sq, 8, 16);
    if (seg == 0) nrm[row] = sq;
    ushort4 hv = {h[0], h[1], h[2], h[3]}, lv = {l[0], l[1], l[2], l[3]};
    reinterpret_cast<ushort4*>(xh)[t] = hv;
    reinterpret_cast<ushort4*>(xl)[t] = lv;
}

// K2a: MFMA tau partials. Block = 64 q x 2048 samples (16 chunks of 128).
// Per (lane, q-row) a branchless depth-2 ladder (min + clamp = 3 VALU/key) over
// the 32 sample keys that lane sees -> 128 partials/query to global.
// grid = NQ/64 = 256 blocks of 256 (4 waves; wave w owns sample-cols w*32..+31).
__global__ void __launch_bounds__(256) tau_p(const unsigned short* __restrict__ xh,
                                             const unsigned short* __restrict__ xl,
                                             const float* __restrict__ nrm,
                                             float* __restrict__ part) {
    __shared__ alignas(16) unsigned short A[128 * 64];    // 16 KB: rows 0-63 q-hi, 64-127 q-lo
    __shared__ alignas(16) unsigned short Bb[256 * 64];   // 32 KB: rows 0-127 s-hi, 128-255 s-lo
    __shared__ float nrmb[128];
    const int tid = (int)threadIdx.x;
    const int q0g = (int)blockIdx.x * 64;                 // global query base
    const int b   = q0g >> 13;                            // uniform (64 | 8192)
    const int n0  = q0g & (N_ - 1);
    const unsigned short* __restrict__ xhb = xh + (size_t)b * N_ * D_;
    const unsigned short* __restrict__ xlb = xl + (size_t)b * N_ * D_;
    const float* __restrict__ nb = nrm + b * N_;

#pragma unroll
    for (int k = 0; k < 4; ++k) {                         // stage A: 128 rows x 8 segs
        int u = tid + k * 256, r = u >> 3, s = u & 7;
        const unsigned short* src = (r < 64) ? xhb + (size_t)(n0 + r) * D_
                                             : xlb + (size_t)(n0 + r - 64) * D_;
        *(float4*)((char*)A + SWZ(r, s)) = *(const float4*)((const char*)src + (s << 4));
    }

    const int wave = tid >> 6, lane = tid & 63;
    const int l15 = lane & 15, quad = lane >> 4;

    float lad0[16], lad1[16];
#pragma unroll
    for (int j = 0; j < 16; ++j) { lad0[j] = __builtin_inff(); lad1[j] = __builtin_inff(); }

    for (int mc = 0; mc < 16; ++mc) {
        const int m0 = mc * 128;
        __syncthreads();                                  // A visible / prev compute done
#pragma unroll
        for (int k = 0; k < 8; ++k) {                     // stage B chunk (hi+lo)
            int u = tid + k * 256, r = u >> 3, s = u & 7;
            const unsigned short* src = (r < 128) ? xhb + (size_t)(m0 + r) * D_
                                                  : xlb + (size_t)(m0 + r - 128) * D_;
            *(float4*)((char*)Bb + SWZ(r, s)) = *(const float4*)((const char*)src + (s << 4));
        }
        if (tid < 128) nrmb[tid] = nb[m0 + tid];
        __syncthreads();

        f32x4 acc[4][2] = {};
#pragma unroll
        for (int half = 0; half < 2; ++half) {
            const int seg = half * 4 + quad;
            bf16x8 afh[4], afl[4], bfh[2], bfl[2];
#pragma unroll
            for (int tm = 0; tm < 4; ++tm) {
                afh[tm] = *(const bf16x8*)((const char*)A + SWZ(tm * 16 + l15, seg));
                afl[tm] = *(const bf16x8*)((const char*)A + SWZ(64 + tm * 16 + l15, seg));
            }
#pragma unroll
            for (int tn = 0; tn < 2; ++tn) {
                bfh[tn] = *(const bf16x8*)((const char*)Bb + SWZ(wave * 32 + tn * 16 + l15, seg));
                bfl[tn] = *(const bf16x8*)((const char*)Bb + SWZ(128 + wave * 32 + tn * 16 + l15, seg));
            }
#pragma unroll
            for (int tm = 0; tm < 4; ++tm)
#pragma unroll
                for (int tn = 0; tn < 2; ++tn) {
                    acc[tm][tn] = __builtin_amdgcn_mfma_f32_16x16x32_bf16(afh[tm], bfh[tn], acc[tm][tn], 0, 0, 0);
                    acc[tm][tn] = __builtin_amdgcn_mfma_f32_16x16x32_bf16(afh[tm], bfl[tn], acc[tm][tn], 0, 0, 0);
                    acc[tm][tn] = __builtin_amdgcn_mfma_f32_16x16x32_bf16(afl[tm], bfh[tn], acc[tm][tn], 0, 0, 0);
                }
        }
        // epilogue: C/D col=lane&15 (sample), row=quad*4+reg (query); depth-2 ladder
#pragma unroll
        for (int tn = 0; tn < 2; ++tn) {
            const float nm = nrmb[wave * 32 + tn * 16 + l15];
#pragma unroll
            for (int tm = 0; tm < 4; ++tm)
#pragma unroll
                for (int reg = 0; reg < 4; ++reg) {
                    float keyf = fmaf(-2.f, acc[tm][tn][reg], nm);
                    const int li = tm * 4 + reg;
                    float k0 = lad0[li];
                    lad0[li] = fminf(k0, keyf);
                    lad1[li] = fminf(fmaxf(keyf, k0), lad1[li]);   // clamp = med3
                }
        }
    }
    // dump partials: part[q][wave*16+l15] as float2
#pragma unroll
    for (int tm = 0; tm < 4; ++tm)
#pragma unroll
        for (int reg = 0; reg < 4; ++reg) {
            const int r = tm * 16 + quad * 4 + reg;
            const int li = tm * 4 + reg;
            float2 v = {lad0[li], lad1[li]};
            *(float2*)(part + ((size_t)(q0g + r)) * 128 + (wave * 16 + l15) * 2) = v;
        }
}

// K2b: merge 128 partials/query -> tau. Thread per query; grid = NQ/256 = 64.
__global__ void __launch_bounds__(256) tau_m(const float* __restrict__ part,
                                             float* __restrict__ tau) {
    const int q = blockIdx.x * 256 + (int)threadIdx.x;
    const float4* p = reinterpret_cast<const float4*>(part + (size_t)q * 128);
    float key[K_];
#pragma unroll
    for (int j = 0; j < K_; ++j) key[j] = __builtin_inff();
    for (int i = 0; i < 32; ++i) {
        float4 v = p[i];
        topk_insertf<K_>(key, v.x); topk_insertf<K_>(key, v.y);
        topk_insertf<K_>(key, v.z); topk_insertf<K_>(key, v.w);
    }
    tau[q] = key[15] + SLOP;
}

// K3: MFMA filter, B-reuse. Block = 128q x 1024m (8 chunks of 128m). A (hi+lo,
// 32 KB) staged once; B per chunk (32 KB). 3-term bf16 split. XOR-swizzled LDS.
// Accepts -> LDS per-query lists (DS atomics only), flushed to fixed per-(q,ms)
// global slots. grid = 2*64*8 = 1024 blocks of 256.
__global__ void __launch_bounds__(256, 2) filter_k(const unsigned short* __restrict__ xh,
                                                   const unsigned short* __restrict__ xl,
                                                   const float* __restrict__ nrm,
                                                   const float* __restrict__ tau,
                                                   unsigned short* __restrict__ cnt_pb,
                                                   unsigned short* __restrict__ buf2) {
    __shared__ alignas(16) unsigned short A[256 * 64];    // 32 KB: rows 0-127 hi, 128-255 lo
    __shared__ alignas(16) unsigned short Bb[256 * 64];   // 32 KB
    __shared__ alignas(16) float taub[128];
    __shared__ unsigned short lists[128 * CAPB];          // 12 KB
    __shared__ unsigned int cntL[128];
    const int tid = (int)threadIdx.x;
    const int bid = (int)blockIdx.x;
    const int b  = bid >> 9;
    const int qt = (bid >> 3) & 63;
    const int ms = bid & 7;
    const int q0 = qt * 128;
    const unsigned short* __restrict__ xhb = xh + (size_t)b * N_ * D_;
    const unsigned short* __restrict__ xlb = xl + (size_t)b * N_ * D_;
    const float* __restrict__ nb = nrm + b * N_;

#pragma unroll
    for (int k = 0; k < 8; ++k) {
        int u = tid + k * 256, r = u >> 3, s = u & 7;
        const unsigned short* src = (r < 128) ? xhb + (size_t)(q0 + r) * D_
                                              : xlb + (size_t)(q0 + r - 128) * D_;
        *(float4*)((char*)A + SWZ(r, s)) = *(const float4*)((const char*)src + (s << 4));
    }
    if (tid < 128) { cntL[tid] = 0; taub[tid] = tau[(b << 13) + q0 + tid]; }

    const int wave = tid >> 6, lane = tid & 63;
    const int wq = wave >> 1, wm = wave & 1;              // 64x64 wave subtile
    const int l15 = lane & 15, quad = lane >> 4;

    for (int mc = 0; mc < 8; ++mc) {
        const int m0 = ms * 1024 + mc * 128;
        __syncthreads();
#pragma unroll
        for (int k = 0; k < 8; ++k) {
            int u = tid + k * 256, r = u >> 3, s = u & 7;
            const unsigned short* src = (r < 128) ? xhb + (size_t)(m0 + r) * D_
                                                  : xlb + (size_t)(m0 + r - 128) * D_;
            *(float4*)((char*)Bb + SWZ(r, s)) = *(const float4*)((const char*)src + (s << 4));
        }
        __syncthreads();

        f32x4 acc[4][4] = {};
#pragma unroll
        for (int sp = 0; sp < 3; ++sp) {
            const int abase = (sp == 2) ? 128 : 0;         // A: hi,hi,lo
            const int bbase = (sp == 1) ? 128 : 0;         // B: hi,lo,hi
#pragma unroll
            for (int half = 0; half < 2; ++half) {
                const int seg = half * 4 + quad;
                bf16x8 af[4], bfr[4];
#pragma unroll
                for (int tm = 0; tm < 4; ++tm) {
                    int r = abase + wq * 64 + tm * 16 + l15;
                    af[tm] = *(const bf16x8*)((const char*)A + SWZ(r, seg));
                }
#pragma unroll
                for (int tn = 0; tn < 4; ++tn) {
                    int r = bbase + wm * 64 + tn * 16 + l15;
                    bfr[tn] = *(const bf16x8*)((const char*)Bb + SWZ(r, seg));
                }
#pragma unroll
                for (int tm = 0; tm < 4; ++tm)
#pragma unroll
                    for (int tn = 0; tn < 4; ++tn)
                        acc[tm][tn] = __builtin_amdgcn_mfma_f32_16x16x32_bf16(af[tm], bfr[tn], acc[tm][tn], 0, 0, 0);
            }
        }

        // epilogue: C/D layout col=lane&15 (m), row=quad*4+reg (q)
#pragma unroll
        for (int tm = 0; tm < 4; ++tm) {
            const f32x4 t4 = *(const f32x4*)(taub + wq * 64 + tm * 16 + quad * 4);
#pragma unroll
            for (int tn = 0; tn < 4; ++tn) {
                const int mid = m0 + wm * 64 + tn * 16 + l15;
                const float nm = nb[mid];
#pragma unroll
                for (int reg = 0; reg < 4; ++reg) {
                    float keyf = fmaf(-2.f, acc[tm][tn][reg], nm);
                    if (keyf <= t4[reg] + SLOP) {
                        int ql = wq * 64 + tm * 16 + quad * 4 + reg;     // local q
                        unsigned pos = atomicAdd(&cntL[ql], 1u);         // LDS atomic
                        if (pos < CAPB) lists[ql * CAPB + pos] = (unsigned short)mid;
                    }
                }
            }
        }
    }
    __syncthreads();
    if (tid < 128) {                                       // flush to fixed slots
        int q = (b << 13) + q0 + tid;
        unsigned cn = cntL[tid]; cn = cn < CAPB ? cn : CAPB;
        cnt_pb[(size_t)q * MS + ms] = (unsigned short)cn;
        unsigned short* dst = buf2 + ((size_t)q * MS + ms) * CAPB;
        for (unsigned i = 0; i < cn; ++i) dst[i] = lists[tid * CAPB + i];
    }
}

// K4: exact f64 rerank. 16 lanes per query; per candidate one coalesced 256 B row
// load, 4 f64 FMA/lane, 4-step shfl reduce, u64 ladder (exact (dist,id) order).
// block 256 = 16 queries; grid = 1024.
__global__ void __launch_bounds__(256, 4) rerank_k(const float* __restrict__ x,
                                                   const unsigned short* __restrict__ cnt_pb,
                                                   const unsigned short* __restrict__ buf2,
                                                   int* __restrict__ out) {
    const int tid = (int)threadIdx.x;
    const int grp = tid >> 4, l = tid & 15;
    const int q = blockIdx.x * 16 + grp;
    const int b = q >> 13, n = q & (N_ - 1);
    const float* __restrict__ xb = x + (size_t)b * N_ * D_;
    const float4 Qv = *(const float4*)(xb + (size_t)n * D_ + l * 4);
    const double qx = Qv.x, qy = Qv.y, qz = Qv.z, qw = Qv.w;

    unsigned long long key[K_];
#pragma unroll
    for (int j = 0; j < K_; ++j) key[j] = ~0ull;

    for (int ms = 0; ms < MS; ++ms) {
        const int cn = (int)cnt_pb[(size_t)q * MS + ms];
        const unsigned short* bp = buf2 + ((size_t)q * MS + ms) * CAPB;
        for (int i = 0; i < cn; ++i) {
            const int id = (int)bp[i];
            const float4 cv = *(const float4*)(xb + (size_t)id * D_ + l * 4);
            double d0 = qx - (double)cv.x, d1 = qy - (double)cv.y;
            double d2 = qz - (double)cv.z, d3 = qw - (double)cv.w;
            double s = fma(d0, d0, fma(d1, d1, fma(d2, d2, d3 * d3)));
            s += __shfl_xor(s, 1, 16); s += __shfl_xor(s, 2, 16);
            s += __shfl_xor(s, 4, 16); s += __shfl_xor(s, 8, 16);
            // s >= 0 -> f64 bits order-preserving; low 13 mantissa bits carry the id
            // for exact (dist, id) lexicographic compare (ties -> lower id).
            unsigned long long kb = (unsigned long long)__double_as_longlong(s);
            topk_insert64<K_>(key, (kb & ~0x1FFFull) | (unsigned)id);
        }
    }
    if (l == 0) {
        int* o1 = out + (size_t)q * K_;                    // nn_idx    [b][n][k]
        int* o2 = out + (size_t)NQ * K_ + (size_t)q * K_;  // center_idx[b][n][k]
#pragma unroll
        for (int kk = 0; kk < K_; ++kk) {
            o1[kk] = (int)(key[kk] & 0x1FFFull);
            o2[kk] = n;
        }
    }
}

extern "C" void kernel_launch(void* const* d_in, const int* in_sizes, int n_in,
                              void* d_out, int out_size, void* d_ws, size_t ws_size,
                              hipStream_t stream) {
    const float* x = (const float*)d_in[0];
    int* out = (int*)d_out;
    char* ws = (char*)d_ws;
    float*          nrm    = (float*)ws;                          //  64 KB @ 0
    float*          tau    = (float*)(ws + (64 << 10));           //  64 KB
    unsigned short* cnt_pb = (unsigned short*)(ws + (128 << 10)); // 256 KB (16384*8*2)
    unsigned short* xh     = (unsigned short*)(ws + (1 << 20));   //   2 MB
    unsigned short* xl     = (unsigned short*)(ws + (3 << 20));   //   2 MB
    unsigned short* buf2   = (unsigned short*)(ws + (5 << 20));   // 12.6 MB (16384*8*48*2)
    float*          part   = (float*)(ws + (5 << 20));            //   8 MB, ALIASES buf2:
    // part is written by tau_p and fully consumed by tau_m BEFORE filter_k writes buf2.

    hipLaunchKernelGGL(split_k,  dim3(1024), dim3(256), 0, stream, x, xh, xl, nrm);
    hipLaunchKernelGGL(tau_p,    dim3(256),  dim3(256), 0, stream, xh, xl, nrm, part);
    hipLaunchKernelGGL(tau_m,    dim3(64),   dim3(256), 0, stream, part, tau);
    hipLaunchKernelGGL(filter_k, dim3(1024), dim3(256), 0, stream, xh, xl, nrm, tau, cnt_pb, buf2);
    hipLaunchKernelGGL(rerank_k, dim3(1024), dim3(256), 0, stream, x, cnt_pb, buf2, out);
}